// Round 8
// baseline (34.269 us; speedup 1.0000x reference)
//
#include <hip/hip_runtime.h>

#define NPTS    8192
#define BATCH   2
#define CH      64
#define NGROUPS 50

#define TS      256                   // square tile side
#define NROW    32                    // NPTS/TS
#define NTILEB  (NROW*(NROW+1)/2)     // 528 triangle tiles per batch
#define MAINPB  (NTILEB*2)            // 1056 half-tiles (256i x 128j) per batch
#define MAINB   (BATCH*MAINPB)        // 2112 blocks total (corr fused into first 400)
#define NBUCK   (BATCH*NGROUPS)       // 100
#define CORRB   (NBUCK*4)             // 400
#define PAD     256                   // bucket capacity

// ------------- Kernel 1: Fsim packed {x,y,z,|f|^2} + per-label index compaction -------------
__global__ __launch_bounds__(256) void fsim_kernel(
    const float* __restrict__ l0, const float* __restrict__ W,
    const float* __restrict__ bias, const int* __restrict__ target,
    float4* __restrict__ fj4, int* __restrict__ gidx, int* __restrict__ gcnt)
{
    const int bid = blockIdx.x, tid = threadIdx.x;

    if (bid < 256) {
        __shared__ float sW[3 * CH];
        if (tid < 3 * CH) sW[tid] = W[tid];
        __syncthreads();
        const int lane = tid & 63, wave = tid >> 6;
        const int p = lane & 15, cg = lane >> 4;
        const int pt = bid * 64 + wave * 16 + p;
        const int b = pt >> 13, n = pt & (NPTS - 1);
        const float* basep = l0 + (size_t)b * CH * NPTS + n;
        float ax = 0.f, ay = 0.f, az = 0.f;
        #pragma unroll
        for (int k = 0; k < 16; ++k) {
            int c = cg * 16 + k;
            float v = basep[(size_t)c * NPTS];
            ax = fmaf(sW[c], v, ax);
            ay = fmaf(sW[CH + c], v, ay);
            az = fmaf(sW[2*CH + c], v, az);
        }
        ax += __shfl_down(ax,32,64); ay += __shfl_down(ay,32,64); az += __shfl_down(az,32,64);
        ax += __shfl_down(ax,16,64); ay += __shfl_down(ay,16,64); az += __shfl_down(az,16,64);
        if (cg == 0) {
            float X = ax + bias[0], Y = ay + bias[1], Z = az + bias[2];
            fj4[pt] = make_float4(X, Y, Z, fmaf(X, X, fmaf(Y, Y, Z * Z)));
        }
    } else {
        // ---- index compaction for bucket (b, L) ----
        const int bucket = bid - 256;
        const int b = bucket / NGROUPS, L = bucket % NGROUPS;
        const int tbase = b * NPTS;
        __shared__ int scnt[256];
        int cnt = 0;
        const int4* t4 = (const int4*)&target[tbase];
        #pragma unroll
        for (int k8 = 0; k8 < 8; ++k8) {
            int4 tv = t4[tid * 8 + k8];
            cnt += (tv.x == L) + (tv.y == L) + (tv.z == L) + (tv.w == L);
        }
        scnt[tid] = cnt;
        __syncthreads();
        for (int s = 1; s < 256; s <<= 1) {       // Hillis-Steele inclusive scan
            int a = (tid >= s) ? scnt[tid - s] : 0;
            __syncthreads();
            scnt[tid] += a;
            __syncthreads();
        }
        int wpos = scnt[tid] - cnt;               // stable by point index
        for (int k = 0; k < 32; ++k) {
            int idx = tid * 32 + k;
            if (target[tbase + idx] == L) {
                if (wpos < PAD) gidx[bucket * PAD + wpos] = idx;
                ++wpos;
            }
        }
        if (tid == 0) gcnt[bucket] = min(scnt[255], PAD);
    }
}

// ------------- Kernel 2: triangle rr-sum (SMEM j-broadcast) + fused corrections -------------
__global__ __launch_bounds__(256) void pair_kernel(
    const float4* __restrict__ fj4,
    const int* __restrict__ gidx, const int* __restrict__ gcnt,
    double* __restrict__ partials)
{
    const int bid = blockIdx.x, tid = threadIdx.x;
    __shared__ float4 sj[PAD];
    __shared__ double wsum[4];

    float  accv = 0.0f;
    double cadd = 0.0;

    // ---- fused bucket correction in first 400 blocks ----
    if (bid < CORRB) {
        const int bucket = bid >> 2, sub = bid & 3;
        const int b = bucket / NGROUPS;
        const int cnt = gcnt[bucket];
        const int base = b * NPTS;
        {
            float4 pv = make_float4(0.f, 0.f, 0.f, 0.f);
            if (tid < cnt) {
                float4 g = fj4[base + gidx[bucket * PAD + tid]];
                pv = make_float4(g.x, g.y, g.z, 1.0f);
            }
            sj[tid] = pv;
        }
        __syncthreads();
        const int pp = sub * 64 + (tid & 63);
        const int g0 = (tid >> 6) * 64;
        if (pp < cnt) {
            const float4 a = sj[pp];
            float accB = 0.f;
            #pragma unroll 4
            for (int qq = g0; qq < g0 + 64; ++qq) {
                float4 c = sj[qq];
                float dx = a.x - c.x, dy = a.y - c.y, dz = a.z - c.z;
                float t = fmaf(dx, dx, fmaf(dy, dy, fmaf(dz, dz, 1.0f)));
                float rr = __builtin_amdgcn_rcpf(t); rr = rr * rr;
                accB = fmaf(fmaf(-2.0f, rr, t), c.w, accB);   // mask via c.w
            }
            accv = accB;
        }
        if (sub == 0 && tid == 0) {
            double c = (double)cnt;
            cadd = 2.0 * c - c * c;   // Sum_{p!=q}(d-2rr) = Sum_all(t-2rr) - c^2 + 2c
        }
        __syncthreads();
    }

    // ---- uniform half-tile: 256 i's x 128 j's = 32K pairs ----
    {
        const int b   = bid / MAINPB;
        const int r   = bid % MAINPB;
        const int tau = r >> 1, half = r & 1;
        int ti = (int)(32.5f - sqrtf(32.5f * 32.5f - 2.0f * (float)tau));
        if (ti < 0) ti = 0; if (ti > NROW - 1) ti = NROW - 1;
        while ((ti + 1) * (65 - (ti + 1)) / 2 <= tau) ++ti;   // cum(r)=r*(65-r)/2
        while (ti * (65 - ti) / 2 > tau) --ti;
        const int tj = ti + (tau - ti * (65 - ti) / 2);

        const int base = b * NPTS;
        const int ib = base + ti * TS + (tid & 63) * 4;
        const float4 p0 = fj4[ib + 0], p1 = fj4[ib + 1];
        const float4 p2 = fj4[ib + 2], p3 = fj4[ib + 3];
        const float nx[4] = {-2.f*p0.x, -2.f*p1.x, -2.f*p2.x, -2.f*p3.x};
        const float ny[4] = {-2.f*p0.y, -2.f*p1.y, -2.f*p2.y, -2.f*p3.y};
        const float nz[4] = {-2.f*p0.z, -2.f*p1.z, -2.f*p2.z, -2.f*p3.z};
        const float si[4] = {p0.w+1.f, p1.w+1.f, p2.w+1.f, p3.w+1.f};

        // wave-uniform j-base -> forced scalar so fj4[jb+jj] becomes s_load_dwordx4
        const int jb = __builtin_amdgcn_readfirstlane(
                           base + tj * TS + half * 128 + (tid >> 6) * 32);

        float acc[4] = {0.f, 0.f, 0.f, 0.f};
        #pragma unroll 8
        for (int jj = 0; jj < 32; ++jj) {
            const float4 q = fj4[jb + jj];      // uniform address: SMEM pipe, no LDS
            #pragma unroll
            for (int u = 0; u < 4; ++u) {
                float t = si[u] + q.w;
                t = fmaf(nx[u], q.x, t);
                t = fmaf(ny[u], q.y, t);
                t = fmaf(nz[u], q.z, t);
                float rcp = __builtin_amdgcn_rcpf(t);
                acc[u] = fmaf(rcp, rcp, acc[u]);
            }
        }
        float s = (acc[0] + acc[1]) + (acc[2] + acc[3]);
        // weights reconstruct 2 * S_all(rr over full ordered matrix incl diag)
        accv += (ti == tj) ? (2.0f * s) : (4.0f * s);
    }

    // ---- block reduction -> one double, plain store ----
    #pragma unroll
    for (int o = 32; o > 0; o >>= 1) accv += __shfl_down(accv, o, 64);
    if ((tid & 63) == 0) wsum[tid >> 6] = (double)accv;
    __syncthreads();
    if (tid == 0)
        partials[bid] = (wsum[0] + wsum[1]) + (wsum[2] + wsum[3]) + cadd;
}

// ------------- Kernel 3: final reduce + scale -------------
__global__ __launch_bounds__(256) void finalize_kernel(
    const double* __restrict__ partials, float* __restrict__ out)
{
    const int tid = threadIdx.x;
    double s = 0.0;
    for (int k = tid; k < MAINB; k += 256) s += partials[k];
    #pragma unroll
    for (int o = 32; o > 0; o >>= 1) s += __shfl_down(s, o, 64);
    __shared__ double sd[4];
    if ((tid & 63) == 0) sd[tid >> 6] = s;
    __syncthreads();
    if (tid == 0) {
        double tot = (sd[0] + sd[1]) + (sd[2] + sd[3]);
        // Sum(partials) = 2*S_all(rr) + corrections; remove 2*diag (rr(0)=1 each)
        tot -= 2.0 * (double)(BATCH * NPTS);
        out[0] = (float)(100.0 * tot / ((double)BATCH * NPTS * NPTS));
    }
}

extern "C" void kernel_launch(void* const* d_in, const int* in_sizes, int n_in,
                              void* d_out, int out_size, void* d_ws, size_t ws_size,
                              hipStream_t stream) {
    const float* l0     = (const float*)d_in[0];   // [2,64,8192]
    const float* W      = (const float*)d_in[1];   // [3,64]
    const float* bias   = (const float*)d_in[2];   // [3]
    const int*   target = (const int*)d_in[3];     // [2,8192]
    float* out = (float*)d_out;

    float4* fj4      = (float4*)d_ws;                               // 16384 * 16B
    double* partials = (double*)((char*)d_ws + BATCH * NPTS * sizeof(float4));
    int*    gidx     = (int*)((char*)partials + MAINB * sizeof(double));
    int*    gcnt     = gidx + NBUCK * PAD;

    fsim_kernel<<<256 + NBUCK, 256, 0, stream>>>(l0, W, bias, target, fj4, gidx, gcnt);
    pair_kernel<<<MAINB, 256, 0, stream>>>(fj4, gidx, gcnt, partials);
    finalize_kernel<<<1, 256, 0, stream>>>(partials, out);
}